// Round 1
// baseline (1771.324 us; speedup 1.0000x reference)
//
#include <hip/hip_runtime.h>
#include <stdint.h>

#define NUM_USERS 20000
#define EMBED_DIM 64
#define KTOP 6            // K+1
#define BLOCK 256
#define NWAVES (BLOCK / 64)

__global__ __launch_bounds__(BLOCK) void topk_blend_kernel(
    const int* __restrict__ user_idx,
    const float* __restrict__ emb,
    const float* __restrict__ cooc,
    float* __restrict__ out)
{
    const int b    = blockIdx.x;
    const int tid  = threadIdx.x;
    const int lane = tid & 63;
    const int wave = tid >> 6;

    const int u = user_idx[b];
    // 64-bit offset: u*20000 floats = up to 1.6e9 bytes -> must not use int32
    const float* row = cooc + (size_t)u * NUM_USERS;

    // ---- per-thread top-6, packed keys sorted descending ----
    // key = (float_bits << 32) | (0xFFFFFFFF - idx)
    // values are in [0,1) so float bits order as unsigned; equal values ->
    // lower idx gives larger key, matching jax.lax.top_k tie-breaking.
    unsigned long long k0 = 0, k1 = 0, k2 = 0, k3 = 0, k4 = 0, k5 = 0;

    const int n4 = NUM_USERS / 4;          // 5000, exact
    const float4* __restrict__ row4 = (const float4*)row;
    for (int i = tid; i < n4; i += BLOCK) {
        float4 v = row4[i];
        const int base = i * 4;
        float vv[4] = {v.x, v.y, v.z, v.w};
        #pragma unroll
        for (int c = 0; c < 4; ++c) {
            unsigned int bits = __float_as_uint(vv[c]);
            unsigned long long key =
                ((unsigned long long)bits << 32) |
                (unsigned long long)(0xFFFFFFFFu - (unsigned)(base + c));
            if (key > k5) {
                k5 = key;
                unsigned long long t;
                if (k5 > k4) { t = k4; k4 = k5; k5 = t; }
                if (k4 > k3) { t = k3; k3 = k4; k4 = t; }
                if (k3 > k2) { t = k2; k2 = k3; k3 = t; }
                if (k2 > k1) { t = k1; k1 = k2; k2 = t; }
                if (k1 > k0) { t = k0; k0 = k1; k1 = t; }
            }
        }
    }

    // ---- wave-level merge: 6 rounds of 64-lane butterfly max on u64 keys ----
    unsigned long long loc[KTOP] = {k0, k1, k2, k3, k4, k5};
    unsigned long long wtop[KTOP];
    int p = 0;
    #pragma unroll
    for (int r = 0; r < KTOP; ++r) {
        unsigned long long cand = (p < KTOP) ? loc[p] : 0ull;
        unsigned long long m = cand;
        #pragma unroll
        for (int off = 32; off > 0; off >>= 1) {
            unsigned long long o = __shfl_xor(m, off, 64);
            if (o > m) m = o;
        }
        wtop[r] = m;
        if (cand == m && m != 0ull) p++;   // keys are unique (idx embedded)
    }

    // ---- cross-wave merge + softmax (thread 0) ----
    __shared__ unsigned long long s_wtop[NWAVES][KTOP];
    __shared__ int   s_idx[KTOP - 1];
    __shared__ float s_w[KTOP - 1];

    if (lane == 0) {
        #pragma unroll
        for (int r = 0; r < KTOP; ++r) s_wtop[wave][r] = wtop[r];
    }
    __syncthreads();

    if (tid == 0) {
        int ptr[NWAVES];
        #pragma unroll
        for (int w = 0; w < NWAVES; ++w) ptr[w] = 0;
        unsigned long long top[KTOP];
        for (int r = 0; r < KTOP; ++r) {
            int best = 0;
            unsigned long long bv = 0;
            #pragma unroll
            for (int w = 0; w < NWAVES; ++w) {
                if (ptr[w] < KTOP) {
                    unsigned long long c = s_wtop[w][ptr[w]];
                    if (c > bv) { bv = c; best = w; }
                }
            }
            top[r] = bv;
            ptr[best]++;
        }
        // drop rank 0; softmax over vals[1..5] (sorted desc -> max is first)
        float vals[KTOP - 1];
        #pragma unroll
        for (int j = 0; j < KTOP - 1; ++j)
            vals[j] = __uint_as_float((unsigned)(top[j + 1] >> 32));
        float mx = vals[0];
        float e[KTOP - 1];
        float sum = 0.f;
        #pragma unroll
        for (int j = 0; j < KTOP - 1; ++j) { e[j] = expf(vals[j] - mx); sum += e[j]; }
        float inv = 1.f / sum;
        #pragma unroll
        for (int j = 0; j < KTOP - 1; ++j) {
            s_idx[j] = (int)(0xFFFFFFFFu - (unsigned)(top[j + 1] & 0xFFFFFFFFull));
            s_w[j]   = e[j] * inv;
        }
    }
    __syncthreads();

    // ---- gather 5 embeddings + blend; one thread per dim (coalesced 256B rows) ----
    if (tid < EMBED_DIM) {
        const int d = tid;
        float acc = 0.f;
        #pragma unroll
        for (int j = 0; j < KTOP - 1; ++j)
            acc += s_w[j] * emb[(size_t)s_idx[j] * EMBED_DIM + d];
        float own = emb[(size_t)u * EMBED_DIM + d];
        out[(size_t)b * EMBED_DIM + d] = 0.7f * own + 0.3f * acc;
    }
}

extern "C" void kernel_launch(void* const* d_in, const int* in_sizes, int n_in,
                              void* d_out, int out_size, void* d_ws, size_t ws_size,
                              hipStream_t stream) {
    const int*   user_idx = (const int*)d_in[0];
    const float* emb      = (const float*)d_in[1];
    const float* cooc     = (const float*)d_in[2];
    float*       out      = (float*)d_out;

    const int batch = in_sizes[0];   // 4096
    topk_blend_kernel<<<batch, BLOCK, 0, stream>>>(user_idx, emb, cooc, out);
}